// Round 2
// baseline (130.441 us; speedup 1.0000x reference)
//
#include <hip/hip_runtime.h>

// N=16, C_X=512, C_W=32, groups=16, H=W=out_h=out_w=64, K=3, PAD=1.
constexpr int NB   = 16;
constexpr int CX   = 512;
constexpr int CW   = 32;
constexpr int GRP  = 16;   // CX / CW
constexpr int HW   = 64;
constexpr int PIX  = HW * HW; // 4096

// One thread per (n, c, oh, quad-of-4-ow); loops over 16 groups.
// All weight/input/output traffic vectorized to dwordx4 where possible.
__global__ __launch_bounds__(256) void agg_kernel(
    const float* __restrict__ in,   // [16][512][64][64]
    const float* __restrict__ wt,   // [16][32][9][4096]
    float* __restrict__ out)        // [16][512][64][64]
{
    int idx = blockIdx.x * 256 + threadIdx.x;
    int qd = idx & 15;           // quad index along ow (4 pixels each)
    int oh = (idx >> 4) & 63;
    int c  = (idx >> 10) & 31;
    int n  = idx >> 15;

    int x   = qd * 4;            // first ow of this thread's quad
    int pix = oh * HW + x;

    // 9 per-pixel weight quads (dwordx4, aligned: pix % 4 == 0).
    const float* wbase = wt + ((size_t)(n * CW + c) * 9) * PIX + pix;
    float4 w[9];
    #pragma unroll
    for (int kk = 0; kk < 9; ++kk)
        w[kk] = *(const float4*)(wbase + (size_t)kk * PIX);

    // Zero weights of out-of-bounds taps; then load from clamped addresses
    // unconditionally (value * 0 contributes nothing).
    if (oh == 0)  {
        w[0] = float4{0,0,0,0}; w[1] = float4{0,0,0,0}; w[2] = float4{0,0,0,0};
    }
    if (oh == 63) {
        w[6] = float4{0,0,0,0}; w[7] = float4{0,0,0,0}; w[8] = float4{0,0,0,0};
    }
    if (x == 0)  { w[0].x = 0.f; w[3].x = 0.f; w[6].x = 0.f; }  // ow==0, left tap
    if (x == 60) { w[2].w = 0.f; w[5].w = 0.f; w[8].w = 0.f; }  // ow==63, right tap

    // Clamped row offsets and edge-column offsets (group-invariant).
    const int r0 = (oh == 0  ? 0  : oh - 1) * HW;
    const int r1 = oh * HW;
    const int r2 = (oh == 63 ? 63 : oh + 1) * HW;
    const int xl = (x == 0  ? 0  : x - 1);  // left edge scalar
    const int xr = (x == 60 ? 63 : x + 4);  // right edge scalar

    const float* ibase = in  + (size_t)(n * CX + c) * PIX;
    float*       obase = out + (size_t)(n * CX + c) * PIX + pix;

    #pragma unroll 2
    for (int g = 0; g < GRP; ++g) {
        const float* ip = ibase + (size_t)g * CW * PIX;
        float4 acc{0.f, 0.f, 0.f, 0.f};
        const int rows[3] = {r0, r1, r2};
        #pragma unroll
        for (int r = 0; r < 3; ++r) {
            float4 qv = *(const float4*)(ip + rows[r] + x);
            float  lv = ip[rows[r] + xl];
            float  rv = ip[rows[r] + xr];
            float4 wl = w[r * 3 + 0];
            float4 wc = w[r * 3 + 1];
            float4 wr = w[r * 3 + 2];
            // left tap reads {lv, qv.x, qv.y, qv.z}
            acc.x = fmaf(wl.x, lv,   acc.x);
            acc.y = fmaf(wl.y, qv.x, acc.y);
            acc.z = fmaf(wl.z, qv.y, acc.z);
            acc.w = fmaf(wl.w, qv.z, acc.w);
            // center tap reads qv
            acc.x = fmaf(wc.x, qv.x, acc.x);
            acc.y = fmaf(wc.y, qv.y, acc.y);
            acc.z = fmaf(wc.z, qv.z, acc.z);
            acc.w = fmaf(wc.w, qv.w, acc.w);
            // right tap reads {qv.y, qv.z, qv.w, rv}
            acc.x = fmaf(wr.x, qv.y, acc.x);
            acc.y = fmaf(wr.y, qv.z, acc.y);
            acc.z = fmaf(wr.z, qv.w, acc.z);
            acc.w = fmaf(wr.w, rv,   acc.w);
        }
        *(float4*)(obase + (size_t)g * CW * PIX) = acc;
    }
}

extern "C" void kernel_launch(void* const* d_in, const int* in_sizes, int n_in,
                              void* d_out, int out_size, void* d_ws, size_t ws_size,
                              hipStream_t stream) {
    const float* in = (const float*)d_in[0];   // (16, 512, 64, 64) f32
    const float* wt = (const float*)d_in[1];   // (16, 32, 9, 4096) f32
    float* out = (float*)d_out;                // (16, 512, 64, 64) f32

    const int total_threads = NB * CW * HW * (HW / 4);  // 524,288
    const int block = 256;
    const int grid = total_threads / block;             // 2048
    agg_kernel<<<grid, block, 0, stream>>>(in, wt, out);
}

// Round 3
// 77.853 us; speedup vs baseline: 1.6755x; 1.6755x over previous
//
#include <hip/hip_runtime.h>

// N=16, C_X=512, C_W=32, groups=16, H=W=out_h=out_w=64, K=3, PAD=1.
constexpr int NB   = 16;
constexpr int CX   = 512;
constexpr int CW   = 32;
constexpr int GRP  = 16;   // CX / CW
constexpr int HW   = 64;
constexpr int PIX  = HW * HW; // 4096

// One thread per (n, c, oh, pair-of-2-ow); loops over 16 groups.
// Weights cached in regs (18 VGPR), halo pixels fetched via __shfl from
// neighbor lanes (row-boundary garbage killed by zeroed edge weights).
__global__ __launch_bounds__(256) void agg_kernel(
    const float* __restrict__ in,   // [16][512][64][64]
    const float* __restrict__ wt,   // [16][32][9][4096]
    float* __restrict__ out)        // [16][512][64][64]
{
    // XCD-chunked swizzle: 4096 blocks, 8 XCDs, bijective since 4096 % 8 == 0.
    int bid = blockIdx.x;
    int wg  = (bid & 7) * (4096 / 8) + (bid >> 3);
    int idx = wg * 256 + threadIdx.x;

    int p  = idx & 31;           // pair index along ow (2 px each)
    int oh = (idx >> 5) & 63;
    int c  = (idx >> 11) & 31;
    int n  = idx >> 16;

    int x   = p * 2;
    int pix = oh * HW + x;

    // 9 per-pixel weight pairs (dwordx2, aligned).
    const float* wp = wt + ((size_t)(n * CW + c) * 9) * PIX + pix;
    float2 w[9];
    #pragma unroll
    for (int kk = 0; kk < 9; ++kk)
        w[kk] = *(const float2*)(wp + (size_t)kk * PIX);

    // Zero weights of out-of-bounds taps (also kills cross-row shuffle garbage:
    // x==0 <=> lane%32==0, x==62 <=> lane%32==31).
    if (oh == 0)  { w[0] = float2{0,0}; w[1] = float2{0,0}; w[2] = float2{0,0}; }
    if (oh == 63) { w[6] = float2{0,0}; w[7] = float2{0,0}; w[8] = float2{0,0}; }
    if (x == 0)   { w[0].x = 0.f; w[3].x = 0.f; w[6].x = 0.f; }
    if (x == 62)  { w[2].y = 0.f; w[5].y = 0.f; w[8].y = 0.f; }

    // Clamped row offsets (group-invariant).
    const int r0 = (oh == 0  ? 0  : oh - 1) * HW;
    const int r1 = oh * HW;
    const int r2 = (oh == 63 ? 63 : oh + 1) * HW;

    const float* ibase = in  + (size_t)(n * CX + c) * PIX;
    float*       obase = out + (size_t)(n * CX + c) * PIX + pix;

    #pragma unroll 2
    for (int g = 0; g < GRP; ++g) {
        const float* ip = ibase + (size_t)g * CW * PIX;
        float2 q0 = *(const float2*)(ip + r0 + x);
        float2 q1 = *(const float2*)(ip + r1 + x);
        float2 q2 = *(const float2*)(ip + r2 + x);
        // Halo pixels from neighbor lanes.
        float l0 = __shfl_up(q0.y, 1), h0 = __shfl_down(q0.x, 1);
        float l1 = __shfl_up(q1.y, 1), h1 = __shfl_down(q1.x, 1);
        float l2 = __shfl_up(q2.y, 1), h2 = __shfl_down(q2.x, 1);

        float ax, ay;
        ax = w[0].x * l0;            ay = w[0].y * q0.x;
        ax = fmaf(w[1].x, q0.x, ax); ay = fmaf(w[1].y, q0.y, ay);
        ax = fmaf(w[2].x, q0.y, ax); ay = fmaf(w[2].y, h0,   ay);
        ax = fmaf(w[3].x, l1,   ax); ay = fmaf(w[3].y, q1.x, ay);
        ax = fmaf(w[4].x, q1.x, ax); ay = fmaf(w[4].y, q1.y, ay);
        ax = fmaf(w[5].x, q1.y, ax); ay = fmaf(w[5].y, h1,   ay);
        ax = fmaf(w[6].x, l2,   ax); ay = fmaf(w[6].y, q2.x, ay);
        ax = fmaf(w[7].x, q2.x, ax); ay = fmaf(w[7].y, q2.y, ay);
        ax = fmaf(w[8].x, q2.y, ax); ay = fmaf(w[8].y, h2,   ay);

        *(float2*)(obase + (size_t)g * CW * PIX) = float2{ax, ay};
    }
}

extern "C" void kernel_launch(void* const* d_in, const int* in_sizes, int n_in,
                              void* d_out, int out_size, void* d_ws, size_t ws_size,
                              hipStream_t stream) {
    const float* in = (const float*)d_in[0];   // (16, 512, 64, 64) f32
    const float* wt = (const float*)d_in[1];   // (16, 32, 9, 4096) f32
    float* out = (float*)d_out;                // (16, 512, 64, 64) f32

    const int total_threads = NB * CW * HW * (HW / 2);  // 1,048,576
    const int block = 256;
    const int grid = total_threads / block;             // 4096
    agg_kernel<<<grid, block, 0, stream>>>(in, wt, out);
}